// Round 8
// baseline (458.154 us; speedup 1.0000x reference)
//
#include <hip/hip_runtime.h>
#include <hip/hip_bf16.h>

#define NB 4
#define NE 1024
#define DIM 128
#define BM 128
#define THREADS 512
#define NBLK 512   // 65536 tokens / 128

typedef __attribute__((ext_vector_type(8))) short bf16x8;
typedef __attribute__((ext_vector_type(4))) float f32x4;

// LDS: A planes (64 KB) + fp32 residual (64 KB) + cand (4 KB) + bidx (512 B)
#define SMEM_RES   65536
#define SMEM_CAND  131072
#define SMEM_BIDX  135168
#define SMEM_TOTAL 135680

__device__ __forceinline__ unsigned short f2bf(float v) {
    __hip_bfloat16 h = __float2bfloat16(v);
    return __builtin_bit_cast(unsigned short, h);
}
__device__ __forceinline__ float bf2f(unsigned short u) {
    __hip_bfloat16 h = __builtin_bit_cast(__hip_bfloat16, u);
    return __bfloat162float(h);
}

#define MFMA(A, B, C) __builtin_amdgcn_mfma_f32_16x16x32_bf16(A, B, C, 0, 0, 0)

// ---- pre-kernel: bake B images (bf16 hi/lo, linear granule layout) + 0.5*||e||^2
// step = (book*4 + nc)*8 + img, img = 2*dg + {0:eh, 1:el}; within a step:
// granule = ksub*256 + code, each 16 B = dims 32*dg + 8*ksub + (0..7)
__global__ __launch_bounds__(64) void rvq_pre(const float* __restrict__ books,
                                              char* __restrict__ bpre,
                                              float* __restrict__ hn) {
    const int bc = blockIdx.x;            // book*1024 + code
    const int book = bc >> 10, code = bc & 1023;
    const int j = threadIdx.x;
    const float* e = books + (size_t)bc * DIM;
    if (j >= 32) return;
    const int jj = j & 15;
    const int d0 = 8 * jj;                // dims d0..d0+7
    float v[8];
#pragma unroll
    for (int m = 0; m < 8; ++m) v[m] = e[d0 + m];
    uint u[4];
    if (j < 16) {                         // hi image
#pragma unroll
        for (int m = 0; m < 4; ++m)
            u[m] = (uint)f2bf(v[2*m]) | ((uint)f2bf(v[2*m+1]) << 16);
    } else {                              // lo image: el = bf16(e - f32(eh))
#pragma unroll
        for (int m = 0; m < 4; ++m) {
            float l0 = v[2*m]   - bf2f(f2bf(v[2*m]));
            float l1 = v[2*m+1] - bf2f(f2bf(v[2*m+1]));
            u[m] = (uint)f2bf(l0) | ((uint)f2bf(l1) << 16);
        }
    }
    const int img  = ((jj >> 2) << 1) | (j >> 4);   // eh even, el odd, per dim-group
    const int ksub = jj & 3;
    const int nc = code >> 8, cic = code & 255;
    const int G = ((((book*4 + nc)*8 + img)*4 + ksub) << 8) + cic;
    *(uint4*)(bpre + (size_t)G * 16) = make_uint4(u[0], u[1], u[2], u[3]);
    if (j < 16) {                         // norms
        float s = 0.f;
#pragma unroll
        for (int m = 0; m < 8; ++m) s += v[m] * v[m];
#pragma unroll
        for (int off = 1; off < 16; off <<= 1) s += __shfl_xor(s, off);
        if (jj == 0) hn[bc] = 0.5f * s;
    }
}

// write token's residual slice as bf16 hi/lo into A planes (swizzled rows)
// plane hi = seg*4+g, lo = 16+seg*4+g (g = dim-granule); row = tok ^ (g<<1)
__device__ __forceinline__ void write_A(char* smem, const float* r, int tok, int seg) {
#pragma unroll
    for (int g = 0; g < 4; ++g) {
        uint uh[4], ul[4];
#pragma unroll
        for (int m = 0; m < 4; ++m) {
            float v0 = r[8*g + 2*m], v1 = r[8*g + 2*m + 1];
            unsigned short h0 = f2bf(v0), h1 = f2bf(v1);
            float l0 = v0 - bf2f(h0), l1 = v1 - bf2f(h1);
            uh[m] = (uint)h0 | ((uint)h1 << 16);
            ul[m] = (uint)f2bf(l0) | ((uint)f2bf(l1) << 16);
        }
        const int rw = tok ^ (g << 1);
        *(uint4*)(smem + (((seg*4 + g)      << 7) + rw) * 16) = make_uint4(uh[0], uh[1], uh[2], uh[3]);
        *(uint4*)(smem + (((16 + seg*4 + g) << 7) + rw) * 16) = make_uint4(ul[0], ul[1], ul[2], ul[3]);
    }
}

__global__ __launch_bounds__(THREADS, 1) void rvq_mfma(
        const float* __restrict__ z, const float* __restrict__ books,
        const char* __restrict__ bpre, const float* __restrict__ hn,
        float* __restrict__ out) {
    extern __shared__ char smem[];
    const int tid = threadIdx.x;
    const int wid = tid >> 6, lane = tid & 63;
    const int lr = lane & 15, lh = lane >> 4;   // C: col=lr, row base=lh*4
    const int mw = wid >> 2, nw = wid & 3;      // wave grid 2M x 4N
    const int tok = tid & 127, seg = tid >> 7;  // update ownership
    const int lrs = lr ^ (lh << 1);             // swizzled row-within-16

    const int t0 = blockIdx.x * BM;
    const int bb = t0 >> 11, tin = t0 & 2047;
    const size_t zbase = (size_t)bb * (DIM * 2048) + tin;

    // thread-private fp32 residual row in LDS (128 B, granule-swizzled)
    char* rrow = smem + SMEM_RES + (seg * 128 + tok) * 128;
    const int rsw7 = tok & 7;

    {   // init: residual = z slice (transposed read), to A planes + resl
        float r[32];
#pragma unroll
        for (int jv = 0; jv < 32; ++jv)
            r[jv] = z[zbase + (size_t)(32*seg + jv) * 2048 + tok];
        write_A(smem, r, tok, seg);
#pragma unroll
        for (int g = 0; g < 8; ++g)
            *(float4*)(rrow + ((g ^ rsw7) << 4)) =
                make_float4(r[4*g], r[4*g+1], r[4*g+2], r[4*g+3]);
    }

    // per-lane bases: B fragment (global) and A fragment (LDS)
    const char* vB = bpre + ((lh << 8) + (nw << 6) + lr) * 16;
    const char* aA = smem + lh * 2048 + ((mw << 6) + lrs) * 16;

    for (int book = 0; book < NB; ++book) {
        float bval[4][4];
        int bcode[4][4];
#pragma unroll
        for (int a = 0; a < 4; ++a)
#pragma unroll
            for (int b = 0; b < 4; ++b) { bval[a][b] = -1e30f; bcode[a][b] = 0; }

        const char* bkB = vB + (size_t)book * (32 * 16384);
        bf16x8 bv0 = *(const bf16x8*)(bkB);
        bf16x8 bv1 = *(const bf16x8*)(bkB + 256);
        bf16x8 bv2 = *(const bf16x8*)(bkB + 512);
        bf16x8 bv3 = *(const bf16x8*)(bkB + 768);
        __syncthreads();   // A planes visible to all waves

        for (int nc = 0; nc < 4; ++nc) {
            float hnv[4];
#pragma unroll
            for (int nt = 0; nt < 4; ++nt)
                hnv[nt] = hn[book*NE + (nc << 8) + (nw << 6) + (nt << 4) + lr];
            f32x4 acc[4][4];
#pragma unroll
            for (int a = 0; a < 4; ++a)
#pragma unroll
                for (int b = 0; b < 4; ++b) acc[a][b] = (f32x4){0.f, 0.f, 0.f, 0.f};
            bf16x8 ah[4], al[4];

#pragma unroll
            for (int s = 0; s < 8; ++s) {       // s = 2*dg + {0:eh,1:el}
                const int dg = s >> 1;
                const int sl = (nc << 3) + s + 1;
                const bool pf = (sl < 32);
                bf16x8 n0, n1, n2, n3;
                if (pf) {                        // prefetch next image's fragment
                    const char* p = bkB + (size_t)sl * 16384;
                    n0 = *(const bf16x8*)(p);
                    n1 = *(const bf16x8*)(p + 256);
                    n2 = *(const bf16x8*)(p + 512);
                    n3 = *(const bf16x8*)(p + 768);
                }
                if ((s & 1) == 0) {             // eh image: load A frags for dg
                    const char* pa = aA + dg * 8192;
#pragma unroll
                    for (int mt = 0; mt < 4; ++mt) {
                        ah[mt] = *(const bf16x8*)(pa + mt * 256);
                        al[mt] = *(const bf16x8*)(pa + 32768 + mt * 256);
                    }
                }
                // full 4-panel: (xh + xl) * (eh, el) — both panels every image
#pragma unroll
                for (int mt = 0; mt < 4; ++mt) {
                    acc[mt][0] = MFMA(ah[mt], bv0, acc[mt][0]);
                    acc[mt][1] = MFMA(ah[mt], bv1, acc[mt][1]);
                    acc[mt][2] = MFMA(ah[mt], bv2, acc[mt][2]);
                    acc[mt][3] = MFMA(ah[mt], bv3, acc[mt][3]);
                }
#pragma unroll
                for (int mt = 0; mt < 4; ++mt) {
                    acc[mt][0] = MFMA(al[mt], bv0, acc[mt][0]);
                    acc[mt][1] = MFMA(al[mt], bv1, acc[mt][1]);
                    acc[mt][2] = MFMA(al[mt], bv2, acc[mt][2]);
                    acc[mt][3] = MFMA(al[mt], bv3, acc[mt][3]);
                }
                if (pf) { bv0 = n0; bv1 = n1; bv2 = n2; bv3 = n3; }
            }

            // fold chunk scores into running argmax (codes ascend -> strict '>')
#pragma unroll
            for (int mt = 0; mt < 4; ++mt)
#pragma unroll
                for (int nt = 0; nt < 4; ++nt) {
                    const int code = (nc << 8) + (nw << 6) + (nt << 4) + lr;
                    const float h = hnv[nt];
#pragma unroll
                    for (int rg = 0; rg < 4; ++rg) {
                        float sc = acc[mt][nt][rg] - h;
                        if (sc > bval[mt][rg]) { bval[mt][rg] = sc; bcode[mt][rg] = code; }
                    }
                }
        }

        // reduce across the 16 code-columns (lanes xor 1,2,4,8)
#pragma unroll
        for (int mt = 0; mt < 4; ++mt)
#pragma unroll
            for (int rg = 0; rg < 4; ++rg) {
                float v = bval[mt][rg]; int ix = bcode[mt][rg];
#pragma unroll
                for (int off = 1; off < 16; off <<= 1) {
                    float ov = __shfl_xor(v, off);
                    int oi = __shfl_xor(ix, off);
                    if (ov > v || (ov == v && oi < ix)) { v = ov; ix = oi; }
                }
                if (lr == 0) {
                    int token = mw*64 + mt*16 + lh*4 + rg;
                    ((int2*)(smem + SMEM_CAND))[nw*128 + token] =
                        make_int2(__float_as_int(v), ix);
                }
            }
        __syncthreads();
        if (tid < BM) {   // combine the 4 N-wave candidates
            const int2* cp = (const int2*)(smem + SMEM_CAND);
            float bw = -1e30f; int bi = 0;
#pragma unroll
            for (int w = 0; w < 4; ++w) {
                int2 cd = cp[w*128 + tid];
                float v = __int_as_float(cd.x);
                if (v > bw || (v == bw && cd.y < bi)) { bw = v; bi = cd.y; }
            }
            ((int*)(smem + SMEM_BIDX))[tid] = bi;
        }
        __syncthreads();

        // update: resid -= selected code (LDS round-trip; regs only transiently)
        const int bi = ((const int*)(smem + SMEM_BIDX))[tok];
        const float* eb = books + ((size_t)(book*NE + bi) * DIM + 32*seg);
        float r[32];
#pragma unroll
        for (int g = 0; g < 8; ++g) {
            float4 v = *(const float4*)(rrow + ((g ^ rsw7) << 4));
            float4 q = *(const float4*)(eb + 4*g);
            v.x -= q.x; v.y -= q.y; v.z -= q.z; v.w -= q.w;
            r[4*g+0] = v.x; r[4*g+1] = v.y; r[4*g+2] = v.z; r[4*g+3] = v.w;
            if (book < NB - 1)
                *(float4*)(rrow + ((g ^ rsw7) << 4)) = v;
        }
        if (book < NB - 1) {
            write_A(smem, r, tok, seg);  // scoring reads retired 2 barriers ago
        } else {
            // epilogue: out = z - resid_final (== sum of selected codes)
#pragma unroll
            for (int jv = 0; jv < 32; ++jv) {
                size_t off = zbase + (size_t)(32*seg + jv) * 2048 + tok;
                out[off] = z[off] - r[jv];
            }
        }
    }
}

extern "C" void kernel_launch(void* const* d_in, const int* in_sizes, int n_in,
                              void* d_out, int out_size, void* d_ws, size_t ws_size,
                              hipStream_t stream) {
    const float* z = (const float*)d_in[0];      // [32,128,2048] f32
    const float* books = (const float*)d_in[1];  // [4,1024,128]  f32
    float* out = (float*)d_out;                  // [32,128,2048] f32
    char* bpre = (char*)d_ws;                    // 2 MB B-images
    float* hnp = (float*)((char*)d_ws + 2097152);// 16 KB norms

    hipFuncSetAttribute((const void*)rvq_mfma,
                        hipFuncAttributeMaxDynamicSharedMemorySize, SMEM_TOTAL);
    rvq_pre<<<NB * NE, 64, 0, stream>>>(books, bpre, hnp);
    rvq_mfma<<<NBLK, THREADS, SMEM_TOTAL, stream>>>(z, books, bpre, hnp, out);
}

// Round 9
// 333.166 us; speedup vs baseline: 1.3752x; 1.3752x over previous
//
#include <hip/hip_runtime.h>
#include <hip/hip_bf16.h>

#define NB 4
#define NE 1024
#define DIM 128
#define BM 64
#define THREADS 512
#define NBLK 1024  // 65536 tokens / 64

typedef __attribute__((ext_vector_type(8))) short bf16x8;
typedef __attribute__((ext_vector_type(4))) float f32x4;

// LDS: A planes 32x[64][16B] (32 KB) + fp32 residual (32 KB) + cand (2 KB) + bidx
#define SMEM_RES   32768
#define SMEM_CAND  65536
#define SMEM_BIDX  67584
#define SMEM_TOTAL 67840

__device__ __forceinline__ unsigned short f2bf(float v) {
    __hip_bfloat16 h = __float2bfloat16(v);
    return __builtin_bit_cast(unsigned short, h);
}
__device__ __forceinline__ float bf2f(unsigned short u) {
    __hip_bfloat16 h = __builtin_bit_cast(__hip_bfloat16, u);
    return __bfloat162float(h);
}

#define MFMA(A, B, C) __builtin_amdgcn_mfma_f32_16x16x32_bf16(A, B, C, 0, 0, 0)

// ---- pre-kernel (UNCHANGED, proven): bake B images + 0.5*||e||^2
// step = (book*4 + nc)*8 + img, img = 2*dg + {0:eh, 1:el}; within a step:
// granule = ksub*256 + code, each 16 B = dims 32*dg + 8*ksub + (0..7)
__global__ __launch_bounds__(64) void rvq_pre(const float* __restrict__ books,
                                              char* __restrict__ bpre,
                                              float* __restrict__ hn) {
    const int bc = blockIdx.x;            // book*1024 + code
    const int book = bc >> 10, code = bc & 1023;
    const int j = threadIdx.x;
    const float* e = books + (size_t)bc * DIM;
    if (j >= 32) return;
    const int jj = j & 15;
    const int d0 = 8 * jj;                // dims d0..d0+7
    float v[8];
#pragma unroll
    for (int m = 0; m < 8; ++m) v[m] = e[d0 + m];
    uint u[4];
    if (j < 16) {                         // hi image
#pragma unroll
        for (int m = 0; m < 4; ++m)
            u[m] = (uint)f2bf(v[2*m]) | ((uint)f2bf(v[2*m+1]) << 16);
    } else {                              // lo image: el = bf16(e - f32(eh))
#pragma unroll
        for (int m = 0; m < 4; ++m) {
            float l0 = v[2*m]   - bf2f(f2bf(v[2*m]));
            float l1 = v[2*m+1] - bf2f(f2bf(v[2*m+1]));
            u[m] = (uint)f2bf(l0) | ((uint)f2bf(l1) << 16);
        }
    }
    const int img  = ((jj >> 2) << 1) | (j >> 4);   // eh even, el odd, per dim-group
    const int ksub = jj & 3;
    const int nc = code >> 8, cic = code & 255;
    const int G = ((((book*4 + nc)*8 + img)*4 + ksub) << 8) + cic;
    *(uint4*)(bpre + (size_t)G * 16) = make_uint4(u[0], u[1], u[2], u[3]);
    if (j < 16) {                         // norms
        float s = 0.f;
#pragma unroll
        for (int m = 0; m < 8; ++m) s += v[m] * v[m];
#pragma unroll
        for (int off = 1; off < 16; off <<= 1) s += __shfl_xor(s, off);
        if (jj == 0) hn[bc] = 0.5f * s;
    }
}

// write token's 16-dim residual slice as bf16 hi/lo into A planes
// plane p = seg*2+g holds dims (seg*16+g*8)+0..7; row = tok ^ ((p&3)<<1)
__device__ __forceinline__ void write_A(char* smem, const float* r, int tok, int seg) {
#pragma unroll
    for (int g = 0; g < 2; ++g) {
        uint uh[4], ul[4];
#pragma unroll
        for (int m = 0; m < 4; ++m) {
            float v0 = r[8*g + 2*m], v1 = r[8*g + 2*m + 1];
            unsigned short h0 = f2bf(v0), h1 = f2bf(v1);
            float l0 = v0 - bf2f(h0), l1 = v1 - bf2f(h1);
            uh[m] = (uint)h0 | ((uint)h1 << 16);
            ul[m] = (uint)f2bf(l0) | ((uint)f2bf(l1) << 16);
        }
        const int p = seg * 2 + g;
        const int rw = tok ^ ((p & 3) << 1);
        *(uint4*)(smem + (p << 10) + rw * 16)          = make_uint4(uh[0], uh[1], uh[2], uh[3]);
        *(uint4*)(smem + ((p + 16) << 10) + rw * 16)   = make_uint4(ul[0], ul[1], ul[2], ul[3]);
    }
}

__global__ __launch_bounds__(THREADS, 2) void rvq_mfma(
        const float* __restrict__ z, const float* __restrict__ books,
        const char* __restrict__ bpre, const float* __restrict__ hn,
        float* __restrict__ out) {
    extern __shared__ char smem[];
    const int tid = threadIdx.x;
    const int wid = tid >> 6, lane = tid & 63;
    const int lr = lane & 15, lh = lane >> 4;   // C: col(code)=lr, row base=lh*4
    const int mw = wid >> 2, nw = wid & 3;      // wave grid 2M x 4N
    const int tok = tid & 63, seg = tid >> 6;   // update ownership: 16 dims each
    const int lrs = lr ^ (lh << 1);             // swizzled row-within-16

    const int t0 = blockIdx.x * BM;
    const int bb = t0 >> 11, tin = t0 & 2047;
    const size_t zbase = (size_t)bb * (DIM * 2048) + tin;

    // thread-private fp32 residual: 4 granules in planes [g2*8+seg][tok]
    char* resl = smem + SMEM_RES + (seg * 64 + tok) * 16;

    {   // init: residual = z slice (transposed read), to A planes + resl
        float r[16];
#pragma unroll
        for (int jv = 0; jv < 16; ++jv)
            r[jv] = z[zbase + (size_t)(16*seg + jv) * 2048 + tok];
        write_A(smem, r, tok, seg);
#pragma unroll
        for (int g2 = 0; g2 < 4; ++g2)
            *(float4*)(resl + g2 * 8192) =
                make_float4(r[4*g2], r[4*g2+1], r[4*g2+2], r[4*g2+3]);
    }

    // per-lane bases: B fragment (global) and A fragment (LDS)
    const char* vB = bpre + (lh << 12) + (((nw << 6) + lr) << 4);
    const char* aA = smem + (lh << 10) + (((mw << 5) + lrs) << 4);

    for (int book = 0; book < NB; ++book) {
        float bval[2][4];
        int bcode[2][4];
#pragma unroll
        for (int a = 0; a < 2; ++a)
#pragma unroll
            for (int b = 0; b < 4; ++b) { bval[a][b] = -1e30f; bcode[a][b] = 0; }

        const char* bkB = vB + (size_t)book * (32 * 16384);
        bf16x8 bv0 = *(const bf16x8*)(bkB);
        bf16x8 bv1 = *(const bf16x8*)(bkB + 256);
        bf16x8 bv2 = *(const bf16x8*)(bkB + 512);
        bf16x8 bv3 = *(const bf16x8*)(bkB + 768);
        __syncthreads();   // A planes visible to all waves

        for (int nc = 0; nc < 4; ++nc) {
            float hnv[4];
#pragma unroll
            for (int nt = 0; nt < 4; ++nt)
                hnv[nt] = hn[book*NE + (nc << 8) + (nw << 6) + (nt << 4) + lr];
            f32x4 acc[2][4];
#pragma unroll
            for (int a = 0; a < 2; ++a)
#pragma unroll
                for (int b = 0; b < 4; ++b) acc[a][b] = (f32x4){0.f, 0.f, 0.f, 0.f};
            bf16x8 ah[2], al[2];

#pragma unroll
            for (int s = 0; s < 8; ++s) {       // s = 2*dg + {0:eh,1:el}
                const int dg = s >> 1;
                const int sl = (nc << 3) + s + 1;
                const bool pf = (sl < 32);
                bf16x8 n0, n1, n2, n3;
                if (pf) {                        // prefetch next image's fragment
                    const char* p = bkB + (size_t)sl * 16384;
                    n0 = *(const bf16x8*)(p);
                    n1 = *(const bf16x8*)(p + 256);
                    n2 = *(const bf16x8*)(p + 512);
                    n3 = *(const bf16x8*)(p + 768);
                }
                if ((s & 1) == 0) {             // eh image: load A frags for dg
                    const char* pa = aA + dg * 4096;
#pragma unroll
                    for (int mt = 0; mt < 2; ++mt) {
                        ah[mt] = *(const bf16x8*)(pa + mt * 256);
                        al[mt] = *(const bf16x8*)(pa + 16384 + mt * 256);
                    }
                }
                // full 4-panel: (xh + xl) * (eh, el) — both panels every image
#pragma unroll
                for (int mt = 0; mt < 2; ++mt) {
                    acc[mt][0] = MFMA(ah[mt], bv0, acc[mt][0]);
                    acc[mt][1] = MFMA(ah[mt], bv1, acc[mt][1]);
                    acc[mt][2] = MFMA(ah[mt], bv2, acc[mt][2]);
                    acc[mt][3] = MFMA(ah[mt], bv3, acc[mt][3]);
                }
#pragma unroll
                for (int mt = 0; mt < 2; ++mt) {
                    acc[mt][0] = MFMA(al[mt], bv0, acc[mt][0]);
                    acc[mt][1] = MFMA(al[mt], bv1, acc[mt][1]);
                    acc[mt][2] = MFMA(al[mt], bv2, acc[mt][2]);
                    acc[mt][3] = MFMA(al[mt], bv3, acc[mt][3]);
                }
                if (pf) { bv0 = n0; bv1 = n1; bv2 = n2; bv3 = n3; }
            }

            // fold chunk scores into running argmax (codes ascend -> strict '>')
#pragma unroll
            for (int mt = 0; mt < 2; ++mt)
#pragma unroll
                for (int nt = 0; nt < 4; ++nt) {
                    const int code = (nc << 8) + (nw << 6) + (nt << 4) + lr;
                    const float h = hnv[nt];
#pragma unroll
                    for (int rg = 0; rg < 4; ++rg) {
                        float sc = acc[mt][nt][rg] - h;
                        if (sc > bval[mt][rg]) { bval[mt][rg] = sc; bcode[mt][rg] = code; }
                    }
                }
        }

        // reduce across the 16 code-columns (lanes xor 1,2,4,8)
#pragma unroll
        for (int mt = 0; mt < 2; ++mt)
#pragma unroll
            for (int rg = 0; rg < 4; ++rg) {
                float v = bval[mt][rg]; int ix = bcode[mt][rg];
#pragma unroll
                for (int off = 1; off < 16; off <<= 1) {
                    float ov = __shfl_xor(v, off);
                    int oi = __shfl_xor(ix, off);
                    if (ov > v || (ov == v && oi < ix)) { v = ov; ix = oi; }
                }
                if (lr == 0) {
                    int token = mw*32 + mt*16 + lh*4 + rg;
                    ((int2*)(smem + SMEM_CAND))[nw*64 + token] =
                        make_int2(__float_as_int(v), ix);
                }
            }
        __syncthreads();
        if (tid < BM) {   // combine the 4 N-wave candidates
            const int2* cp = (const int2*)(smem + SMEM_CAND);
            float bw = -1e30f; int bi = 0;
#pragma unroll
            for (int w = 0; w < 4; ++w) {
                int2 cd = cp[w*64 + tid];
                float v = __int_as_float(cd.x);
                if (v > bw || (v == bw && cd.y < bi)) { bw = v; bi = cd.y; }
            }
            ((int*)(smem + SMEM_BIDX))[tid] = bi;
        }
        __syncthreads();

        // update: resid -= selected code (LDS round-trip; regs only transiently)
        const int bi = ((const int*)(smem + SMEM_BIDX))[tok];
        const float* eb = books + ((size_t)(book*NE + bi) * DIM + 16*seg);
        float r[16];
#pragma unroll
        for (int g2 = 0; g2 < 4; ++g2) {
            float4 v = *(const float4*)(resl + g2 * 8192);
            float4 q = *(const float4*)(eb + 4*g2);
            v.x -= q.x; v.y -= q.y; v.z -= q.z; v.w -= q.w;
            r[4*g2+0] = v.x; r[4*g2+1] = v.y; r[4*g2+2] = v.z; r[4*g2+3] = v.w;
            if (book < NB - 1)
                *(float4*)(resl + g2 * 8192) = v;
        }
        if (book < NB - 1) {
            write_A(smem, r, tok, seg);  // scoring reads retired 2 barriers ago
        } else {
            // epilogue: out = z - resid_final (== sum of selected codes)
#pragma unroll
            for (int jv = 0; jv < 16; ++jv) {
                size_t off = zbase + (size_t)(16*seg + jv) * 2048 + tok;
                out[off] = z[off] - r[jv];
            }
        }
    }
}

extern "C" void kernel_launch(void* const* d_in, const int* in_sizes, int n_in,
                              void* d_out, int out_size, void* d_ws, size_t ws_size,
                              hipStream_t stream) {
    const float* z = (const float*)d_in[0];      // [32,128,2048] f32
    const float* books = (const float*)d_in[1];  // [4,1024,128]  f32
    float* out = (float*)d_out;                  // [32,128,2048] f32
    char* bpre = (char*)d_ws;                    // 2 MB B-images
    float* hnp = (float*)((char*)d_ws + 2097152);// 16 KB norms

    hipFuncSetAttribute((const void*)rvq_mfma,
                        hipFuncAttributeMaxDynamicSharedMemorySize, SMEM_TOTAL);
    rvq_pre<<<NB * NE, 64, 0, stream>>>(books, bpre, hnp);
    rvq_mfma<<<NBLK, THREADS, SMEM_TOTAL, stream>>>(z, books, bpre, hnp, out);
}